// Round 1
// baseline (451.867 us; speedup 1.0000x reference)
//
#include <hip/hip_runtime.h>
#include <hip/hip_bf16.h>

// QLSTMClassifier: Embedding -> QLSTM (closed-form quantum layer) -> Linear -> log_softmax
// S=256 (batch==seq), E=1024, H=10, V=50257, T=50.
//
// Pipeline:
//  k_wt   : transpose Wg[4][1034][10] x-part -> Wt[k][c] (k<1024, c=g*10+h), k-major for coalesced staging
//  k_gemm : pre[split][row][40] = emb[idx[row]][krange] @ Wt[krange]   (row = t*256+b), K split 4 ways
//  k_rnn  : per-b sequential recurrence, 1 wave per b. qlayer closed form:
//           c=cos(z+theta); out0=prod_{j>=1} c_j; out_w=prod_{j<=w} c_j
//  k_head : logits = hx @ W_out + b_out; log_softmax
//
// ws layout (floats): Wt[40960] | pre[4*65536*40] | outs[65536*10]   (~44.7 MB)

#define E_DIM 1024
#define H_DIM 10
#define NC 40          // 4 gates * 10
#define EHS 10340      // (E+H)*H = per-gate Wg stride
#define KT 16
#define ALD_STRIDE 516 // 512 rows + 4 pad (keeps 16B align, breaks some conflicts)

// ---------------- kernel 0: Wg -> k-major Wt ----------------
__global__ __launch_bounds__(256) void k_wt(const float* __restrict__ Wg,
                                            float* __restrict__ Wt) {
    int i = blockIdx.x * 256 + threadIdx.x;   // < 1024*40
    if (i < E_DIM * NC) {
        int k = i / NC, c = i % NC;
        int g = c / H_DIM, h = c % H_DIM;
        Wt[i] = Wg[g * EHS + k * H_DIM + h];
    }
}

// ---------------- kernel 1: gathered skinny GEMM ----------------
// grid 512 = 128 row-blocks (BM=512 rows) x 4 K-splits (256 K each). block 256.
// thread: 8 rows x 10 cols accumulators. A staged transposed in LDS [k][row].
__global__ __launch_bounds__(256, 2) void k_gemm(const int* __restrict__ idx,
                                                 const float* __restrict__ emb,
                                                 const float* __restrict__ Wt,
                                                 float* __restrict__ pre) {
    __shared__ float A_lds[KT * ALD_STRIDE];
    __shared__ float W_lds[KT * NC];

    const int tid = threadIdx.x;
    const int rb = blockIdx.x & 127;
    const int split = blockIdx.x >> 7;
    const int rowbase = rb * 512;
    const int k0 = split * 256;
    const int rt = tid >> 2;       // 0..63
    const int cg = tid & 3;        // 0..3
    const int r0 = rt * 8;
    const int c0 = cg * 10;

    // preload the 8 gather indices this thread stages (rows tid/4 + it*64)
    int idx8[8];
#pragma unroll
    for (int it = 0; it < 8; ++it) idx8[it] = idx[rowbase + (tid >> 2) + it * 64];

    float acc[8][10];
#pragma unroll
    for (int r = 0; r < 8; ++r)
#pragma unroll
        for (int c = 0; c < 10; ++c) acc[r][c] = 0.0f;

    for (int kt = 0; kt < 256 / KT; ++kt) {
        const int ktb = k0 + kt * KT;
        __syncthreads();   // previous tile's compute done before overwrite
        // stage W tile (16 x 40 floats = 160 float4)
        if (tid < 160) {
            float4 wv = *(const float4*)(Wt + (size_t)ktb * NC + tid * 4);
            *(float4*)&W_lds[tid * 4] = wv;
        }
        // stage A tile transposed: [k][row]
#pragma unroll
        for (int it = 0; it < 8; ++it) {
            int row = (tid >> 2) + it * 64;
            const float* p = emb + (size_t)idx8[it] * E_DIM + ktb + (tid & 3) * 4;
            float4 v = *(const float4*)p;
            int kl = (tid & 3) * 4;
            A_lds[(kl + 0) * ALD_STRIDE + row] = v.x;
            A_lds[(kl + 1) * ALD_STRIDE + row] = v.y;
            A_lds[(kl + 2) * ALD_STRIDE + row] = v.z;
            A_lds[(kl + 3) * ALD_STRIDE + row] = v.w;
        }
        __syncthreads();
#pragma unroll 4
        for (int k = 0; k < KT; ++k) {
            float4 a0 = *(const float4*)&A_lds[k * ALD_STRIDE + r0];
            float4 a1 = *(const float4*)&A_lds[k * ALD_STRIDE + r0 + 4];
            float w[10];
#pragma unroll
            for (int i = 0; i < 5; ++i) {
                float2 wv = *(const float2*)&W_lds[k * NC + c0 + 2 * i];
                w[2 * i] = wv.x; w[2 * i + 1] = wv.y;
            }
            float ar[8] = {a0.x, a0.y, a0.z, a0.w, a1.x, a1.y, a1.z, a1.w};
#pragma unroll
            for (int r = 0; r < 8; ++r)
#pragma unroll
                for (int c = 0; c < 10; ++c)
                    acc[r][c] = fmaf(ar[r], w[c], acc[r][c]);
        }
    }
    // store partials: pre[split][rowbase+r0+r][c0..c0+9]
#pragma unroll
    for (int r = 0; r < 8; ++r) {
        size_t base = ((size_t)split * 65536 + rowbase + r0 + r) * NC + c0;
#pragma unroll
        for (int i = 0; i < 5; ++i) {
            float2 st = {acc[r][2 * i], acc[r][2 * i + 1]};
            *(float2*)&pre[base + 2 * i] = st;
        }
    }
}

// ---------------- kernel 2: QLSTM recurrence, one wave per b ----------------
template <int CTRL>
__device__ __forceinline__ float dpp1(float x) {
    // shifted value; out-of-range lanes get identity 1.0 (old value, bound_ctrl=false)
    return __int_as_float(__builtin_amdgcn_update_dpp(
        __float_as_int(1.0f), __float_as_int(x), CTRL, 0xF, 0xF, false));
}
#define ROW_SHR(n) (0x110 + (n))
#define ROW_SHL(n) (0x100 + (n))

__global__ __launch_bounds__(64) void k_rnn(const float* __restrict__ pre,
                                            const float* __restrict__ Wg,
                                            const float* __restrict__ bg,
                                            const float* __restrict__ theta,
                                            float* __restrict__ outs) {
    const int lane = threadIdx.x;
    const int b = blockIdx.x;
    const int r = lane >> 4;            // gate 0..3 (f,i,g,o)
    const int h = lane & 15;            // wire; valid < 10
    const int hc = (h < 10) ? h : 9;
    const int c = r * 10 + hc;

    float Wh[10];
#pragma unroll
    for (int j = 0; j < 10; ++j) Wh[j] = Wg[r * EHS + (E_DIM + j) * H_DIM + hc];
    const float bias = bg[c] + theta[c];

    // unified activation: act = aa + bb * rcp(1 + exp(kk*q))
    const float kk = (r == 2) ? 2.0f : -1.0f;   // tanh : sigmoid
    const float aa = (r == 2) ? 1.0f : 0.0f;
    const float bb = (r == 2) ? -2.0f : 1.0f;

    const size_t pstride = (size_t)65536 * NC;
    const float* p = pre + (size_t)b * NC + c;       // row t=0
    float z0 = p[0], z1 = p[pstride], z2 = p[2 * pstride], z3 = p[3 * pstride];
    float cx = 0.0f, hx = 0.0f;

    for (int t = 0; t < 256; ++t) {
        // prefetch t+1 partials (independent of the serial chain)
        int tn = (t + 1 < 256) ? t + 1 : 255;
        const float* pn = pre + ((size_t)tn * 256 + b) * NC + c;
        float n0 = pn[0], n1 = pn[pstride], n2 = pn[2 * pstride], n3 = pn[3 * pstride];

        // broadcast hx[0..9] (owned by lanes 0..9) to all lanes
        float hv0 = __shfl(hx, 0), hv1 = __shfl(hx, 1), hv2 = __shfl(hx, 2),
              hv3 = __shfl(hx, 3), hv4 = __shfl(hx, 4), hv5 = __shfl(hx, 5),
              hv6 = __shfl(hx, 6), hv7 = __shfl(hx, 7), hv8 = __shfl(hx, 8),
              hv9 = __shfl(hx, 9);
        float d0 = fmaf(hv0, Wh[0], fmaf(hv2, Wh[2],
                   fmaf(hv4, Wh[4], fmaf(hv6, Wh[6], hv8 * Wh[8]))));
        float d1 = fmaf(hv1, Wh[1], fmaf(hv3, Wh[3],
                   fmaf(hv5, Wh[5], fmaf(hv7, Wh[7], hv9 * Wh[9]))));
        float z = ((z0 + z1) + (z2 + z3)) + bias + (d0 + d1);

        // c_j = cos(z_j + theta_j); v_cos takes revolutions
        float cc = __builtin_amdgcn_cosf(z * 0.15915494309189535f);

        // inclusive prefix product P[h] = prod_{j<=h} c_j  (sources only lower lanes)
        float pp = cc;
        pp *= dpp1<ROW_SHR(1)>(pp);
        pp *= dpp1<ROW_SHR(2)>(pp);
        pp *= dpp1<ROW_SHR(4)>(pp);
        pp *= dpp1<ROW_SHR(8)>(pp);
        // suffix product S[h] = prod_{j>=h} c_j  (pad lanes h>=10 with identity)
        float ss = (h < 10) ? cc : 1.0f;
        ss *= dpp1<ROW_SHL(1)>(ss);
        ss *= dpp1<ROW_SHL(2)>(ss);
        ss *= dpp1<ROW_SHL(4)>(ss);
        ss *= dpp1<ROW_SHL(8)>(ss);
        float tl = dpp1<ROW_SHL(1)>(ss);     // lane h gets S[h+1]; lane0 -> prod_{j>=1}
        float q = (h == 0) ? tl : pp;

        float e = __expf(kk * q);
        float act = fmaf(bb, __builtin_amdgcn_rcpf(1.0f + e), aa);

        // gather f,i,g,o for wire h (gate rows at lanes h, 16+h, 32+h, 48+h)
        float fv = __shfl(act, h);
        float iv = __shfl(act, 16 + h);
        float gv = __shfl(act, 32 + h);
        float ov = __shfl(act, 48 + h);

        cx = fmaf(fv, cx, iv * gv);
        float e2 = __expf(2.0f * cx);
        float th = fmaf(-2.0f, __builtin_amdgcn_rcpf(1.0f + e2), 1.0f);
        hx = ov * th;

        if (lane < 10) outs[((size_t)t * 256 + b) * H_DIM + lane] = hx;

        z0 = n0; z1 = n1; z2 = n2; z3 = n3;
    }
}

// ---------------- kernel 3: hidden2tag + log_softmax, thread per row ----------------
__global__ __launch_bounds__(256) void k_head(const float* __restrict__ outs,
                                              const float* __restrict__ Wo,
                                              const float* __restrict__ bo,
                                              float* __restrict__ out) {
    const size_t row = blockIdx.x * 256 + threadIdx.x;   // < 65536
    float hx[10];
#pragma unroll
    for (int i = 0; i < 5; ++i) {
        float2 v = *(const float2*)&outs[row * H_DIM + 2 * i];
        hx[2 * i] = v.x; hx[2 * i + 1] = v.y;
    }
    float lg[50];
#pragma unroll
    for (int cI = 0; cI < 50; ++cI) {
        float l = bo[cI];
#pragma unroll
        for (int j = 0; j < 10; ++j) l = fmaf(hx[j], Wo[j * 50 + cI], l);
        lg[cI] = l;
    }
    float m = lg[0];
#pragma unroll
    for (int cI = 1; cI < 50; ++cI) m = fmaxf(m, lg[cI]);
    float sum = 0.0f;
#pragma unroll
    for (int cI = 0; cI < 50; ++cI) sum += __expf(lg[cI] - m);
    float lse = m + __logf(sum);
#pragma unroll
    for (int i = 0; i < 25; ++i) {
        float2 v = {lg[2 * i] - lse, lg[2 * i + 1] - lse};
        *(float2*)&out[row * 50 + 2 * i] = v;
    }
}

extern "C" void kernel_launch(void* const* d_in, const int* in_sizes, int n_in,
                              void* d_out, int out_size, void* d_ws, size_t ws_size,
                              hipStream_t stream) {
    const int*   sentence = (const int*)d_in[0];     // (256,256)
    const float* emb      = (const float*)d_in[1];   // (50257,1024)
    const float* Wg       = (const float*)d_in[2];   // (4,1034,10)
    const float* bg       = (const float*)d_in[3];   // (4,10)
    const float* theta    = (const float*)d_in[4];   // (4,10)
    const float* Wo       = (const float*)d_in[5];   // (10,50)
    const float* bo       = (const float*)d_in[6];   // (50,)
    float* out = (float*)d_out;

    float* ws   = (float*)d_ws;
    float* Wt   = ws;                                  // 40960
    float* pre  = ws + 40960;                          // 4*65536*40
    float* outs = pre + (size_t)4 * 65536 * NC;        // 65536*10

    k_wt<<<160, 256, 0, stream>>>(Wg, Wt);
    k_gemm<<<512, 256, 0, stream>>>(sentence, emb, Wt, pre);
    k_rnn<<<256, 64, 0, stream>>>(pre, Wg, bg, theta, outs);
    k_head<<<256, 256, 0, stream>>>(outs, Wo, bo, out);
}

// Round 2
// 404.948 us; speedup vs baseline: 1.1159x; 1.1159x over previous
//
#include <hip/hip_runtime.h>
#include <hip/hip_bf16.h>

// QLSTMClassifier: Embedding -> QLSTM (closed-form quantum layer) -> Linear -> log_softmax
// S=256 (batch==seq), E=1024, H=10, V=50257, T=50.
//
//  k_wt   : transpose Wg x-part -> Wt[k][c] (k<1024, c=g*10+h)
//  k_gemm : zs[split][b][t][40] = emb[idx[t*256+b]][krange] @ Wt[krange]
//           grid 1024 = 256 t-blocks x 4 K-splits; BM=256 rows = all b of one t.
//           Register-double-buffered staging (prefetch tile kt+1 during compute of kt).
//  k_rnn  : per-b sequential recurrence, 1 wave per b; zs streamed sequentially in t
//           with a depth-4 register ring prefetch.
//  k_head : logits = hx @ W_out + b_out; log_softmax
//
// ws layout (floats): Wt[40960] | zs[4*65536*40] | outs[65536*10]   (~44.7 MB)

#define E_DIM 1024
#define H_DIM 10
#define NC 40          // 4 gates * 10
#define EHS 10340      // (E+H)*H = per-gate Wg stride
#define KT 16
#define ALD 260        // 256 rows + 4 pad

// ---------------- kernel 0: Wg -> k-major Wt ----------------
__global__ __launch_bounds__(256) void k_wt(const float* __restrict__ Wg,
                                            float* __restrict__ Wt) {
    int i = blockIdx.x * 256 + threadIdx.x;   // < 1024*40
    if (i < E_DIM * NC) {
        int k = i / NC, c = i % NC;
        int g = c / H_DIM, h = c % H_DIM;
        Wt[i] = Wg[g * EHS + k * H_DIM + h];
    }
}

// ---------------- kernel 1: gathered skinny GEMM, reg-double-buffered ----------------
// block 256: thread (rt=tid>>2, cg=tid&3); acc rows rt*4..rt*4+3, cols cg*10..+9.
// Stage rows rt+it*64 (it<4), k-chunk cg*4..+3, transposed into A_lds[k][row].
__global__ __launch_bounds__(256, 4) void k_gemm(const int* __restrict__ idx,
                                                 const float* __restrict__ emb,
                                                 const float* __restrict__ Wt,
                                                 float* __restrict__ zs) {
    __shared__ float A_lds[KT * ALD];   // 16.6 KB
    __shared__ float W_lds[KT * NC];    // 2.5 KB

    const int tid = threadIdx.x;
    const int rb = blockIdx.x & 255;      // t index
    const int split = blockIdx.x >> 8;    // K split
    const int rowbase = rb * 256;
    const int k0 = split * 256;
    const int rt = tid >> 2;              // 0..63
    const int cg = tid & 3;               // 0..3
    const int r0 = rt * 4;
    const int c0 = cg * 10;
    const int kl = cg * 4;

    const float* aptr[4];
#pragma unroll
    for (int it = 0; it < 4; ++it) {
        int gi = idx[rowbase + rt + it * 64];
        aptr[it] = emb + (size_t)gi * E_DIM + k0 + kl;
    }

    float acc[4][10];
#pragma unroll
    for (int r = 0; r < 4; ++r)
#pragma unroll
        for (int c = 0; c < 10; ++c) acc[r][c] = 0.0f;

    // prologue: prefetch tile 0 into regs
    float4 v[4];
#pragma unroll
    for (int it = 0; it < 4; ++it) v[it] = *(const float4*)aptr[it];
    float4 wv;
    if (tid < 160) wv = *(const float4*)(Wt + (size_t)k0 * NC + tid * 4);

    for (int kt = 0; kt < 256 / KT; ++kt) {
        __syncthreads();   // previous tile's compute done before overwrite
        // regs -> LDS
#pragma unroll
        for (int it = 0; it < 4; ++it) {
            int row = rt + it * 64;
            A_lds[(kl + 0) * ALD + row] = v[it].x;
            A_lds[(kl + 1) * ALD + row] = v[it].y;
            A_lds[(kl + 2) * ALD + row] = v[it].z;
            A_lds[(kl + 3) * ALD + row] = v[it].w;
        }
        if (tid < 160) *(float4*)&W_lds[tid * 4] = wv;
        __syncthreads();
        // issue next tile's loads (no wait until next iteration's LDS store)
        if (kt < 15) {
#pragma unroll
            for (int it = 0; it < 4; ++it)
                v[it] = *(const float4*)(aptr[it] + (kt + 1) * KT);
            if (tid < 160)
                wv = *(const float4*)(Wt + (size_t)(k0 + (kt + 1) * KT) * NC + tid * 4);
        }
        // compute tile kt
#pragma unroll 4
        for (int k = 0; k < KT; ++k) {
            float4 a = *(const float4*)&A_lds[k * ALD + r0];
            float w[10];
#pragma unroll
            for (int i = 0; i < 5; ++i) {
                float2 t2 = *(const float2*)&W_lds[k * NC + c0 + 2 * i];
                w[2 * i] = t2.x; w[2 * i + 1] = t2.y;
            }
            float ar[4] = {a.x, a.y, a.z, a.w};
#pragma unroll
            for (int r = 0; r < 4; ++r)
#pragma unroll
                for (int c = 0; c < 10; ++c)
                    acc[r][c] = fmaf(ar[r], w[c], acc[r][c]);
        }
    }
    // store: zs[((split*256 + b)*256 + t)*40 + c], b = in-block row, t = rb
#pragma unroll
    for (int r = 0; r < 4; ++r) {
        int b = r0 + r;
        size_t base = ((size_t)(split * 256 + b) * 256 + rb) * NC + c0;
#pragma unroll
        for (int i = 0; i < 5; ++i) {
            float2 st = {acc[r][2 * i], acc[r][2 * i + 1]};
            *(float2*)&zs[base + 2 * i] = st;
        }
    }
}

// ---------------- kernel 2: QLSTM recurrence, one wave per b ----------------
template <int CTRL>
__device__ __forceinline__ float dpp1(float x) {
    // shifted value; out-of-range lanes get identity 1.0 (old value, bound_ctrl=false)
    return __int_as_float(__builtin_amdgcn_update_dpp(
        __float_as_int(1.0f), __float_as_int(x), CTRL, 0xF, 0xF, false));
}
#define ROW_SHR(n) (0x110 + (n))
#define ROW_SHL(n) (0x100 + (n))

__global__ __launch_bounds__(64) void k_rnn(const float* __restrict__ zs,
                                            const float* __restrict__ Wg,
                                            const float* __restrict__ bg,
                                            const float* __restrict__ theta,
                                            float* __restrict__ outs) {
    const int lane = threadIdx.x;
    const int b = blockIdx.x;
    const int r = lane >> 4;            // gate 0..3 (f,i,g,o)
    const int h = lane & 15;            // wire; valid < 10
    const int hc = (h < 10) ? h : 9;
    const int c = r * 10 + hc;

    float Wh[10];
#pragma unroll
    for (int j = 0; j < 10; ++j) Wh[j] = Wg[r * EHS + (E_DIM + j) * H_DIM + hc];
    const float bias = bg[c] + theta[c];

    // unified activation: act = aa + bb * rcp(1 + exp(kk*q))
    const float kk = (r == 2) ? 2.0f : -1.0f;   // tanh : sigmoid
    const float aa = (r == 2) ? 1.0f : 0.0f;
    const float bb = (r == 2) ? -2.0f : 1.0f;

    // zs[split][b][t][40] — sequential in t per split stream
    const size_t sstr = (size_t)256 * 256 * NC;
    const float* p0 = zs + (size_t)b * 256 * NC + c;
    const float* p1 = p0 + sstr;
    const float* p2 = p0 + 2 * sstr;
    const float* p3 = p0 + 3 * sstr;

    // depth-4 register ring prefetch
    float a0[4], a1[4], a2[4], a3[4];
#pragma unroll
    for (int u = 0; u < 4; ++u) {
        a0[u] = p0[u * NC]; a1[u] = p1[u * NC];
        a2[u] = p2[u * NC]; a3[u] = p3[u * NC];
    }

    float cx = 0.0f, hx = 0.0f;

#pragma unroll 4
    for (int t = 0; t < 256; ++t) {
        const int u = t & 3;
        float z40 = ((a0[u] + a1[u]) + (a2[u] + a3[u])) + bias;
        // refill slot u with t+4 (clamped) — independent of the serial chain
        {
            int tn = (t + 4 < 256) ? t + 4 : 255;
            a0[u] = p0[tn * NC]; a1[u] = p1[tn * NC];
            a2[u] = p2[tn * NC]; a3[u] = p3[tn * NC];
        }

        // broadcast hx[0..9] (owned by lanes 0..9) to all lanes
        float hv0 = __shfl(hx, 0), hv1 = __shfl(hx, 1), hv2 = __shfl(hx, 2),
              hv3 = __shfl(hx, 3), hv4 = __shfl(hx, 4), hv5 = __shfl(hx, 5),
              hv6 = __shfl(hx, 6), hv7 = __shfl(hx, 7), hv8 = __shfl(hx, 8),
              hv9 = __shfl(hx, 9);
        float d0 = fmaf(hv0, Wh[0], fmaf(hv2, Wh[2],
                   fmaf(hv4, Wh[4], fmaf(hv6, Wh[6], hv8 * Wh[8]))));
        float d1 = fmaf(hv1, Wh[1], fmaf(hv3, Wh[3],
                   fmaf(hv5, Wh[5], fmaf(hv7, Wh[7], hv9 * Wh[9]))));
        float z = z40 + (d0 + d1);

        // c_j = cos(z_j + theta_j); v_cos takes revolutions
        float cc = __builtin_amdgcn_cosf(z * 0.15915494309189535f);

        // inclusive prefix product P[h] = prod_{j<=h} c_j
        float pp = cc;
        pp *= dpp1<ROW_SHR(1)>(pp);
        pp *= dpp1<ROW_SHR(2)>(pp);
        pp *= dpp1<ROW_SHR(4)>(pp);
        pp *= dpp1<ROW_SHR(8)>(pp);
        // suffix product S[h] (pad lanes h>=10 with identity)
        float ss = (h < 10) ? cc : 1.0f;
        ss *= dpp1<ROW_SHL(1)>(ss);
        ss *= dpp1<ROW_SHL(2)>(ss);
        ss *= dpp1<ROW_SHL(4)>(ss);
        ss *= dpp1<ROW_SHL(8)>(ss);
        float tl = dpp1<ROW_SHL(1)>(ss);     // lane 0 -> prod_{j>=1}
        float q = (h == 0) ? tl : pp;

        float e = __expf(kk * q);
        float act = fmaf(bb, __builtin_amdgcn_rcpf(1.0f + e), aa);

        // gather f,i,g,o for wire h (gate rows at lanes h, 16+h, 32+h, 48+h)
        float fv = __shfl(act, h);
        float iv = __shfl(act, 16 + h);
        float gv = __shfl(act, 32 + h);
        float ov = __shfl(act, 48 + h);

        cx = fmaf(fv, cx, iv * gv);
        float e2 = __expf(2.0f * cx);
        float th = fmaf(-2.0f, __builtin_amdgcn_rcpf(1.0f + e2), 1.0f);
        hx = ov * th;

        if (lane < 10) outs[((size_t)t * 256 + b) * H_DIM + lane] = hx;
    }
}

// ---------------- kernel 3: hidden2tag + log_softmax, thread per row ----------------
__global__ __launch_bounds__(256) void k_head(const float* __restrict__ outs,
                                              const float* __restrict__ Wo,
                                              const float* __restrict__ bo,
                                              float* __restrict__ out) {
    const size_t row = blockIdx.x * 256 + threadIdx.x;   // < 65536
    float hx[10];
#pragma unroll
    for (int i = 0; i < 5; ++i) {
        float2 v = *(const float2*)&outs[row * H_DIM + 2 * i];
        hx[2 * i] = v.x; hx[2 * i + 1] = v.y;
    }
    float lg[50];
#pragma unroll
    for (int cI = 0; cI < 50; ++cI) {
        float l = bo[cI];
#pragma unroll
        for (int j = 0; j < 10; ++j) l = fmaf(hx[j], Wo[j * 50 + cI], l);
        lg[cI] = l;
    }
    float m = lg[0];
#pragma unroll
    for (int cI = 1; cI < 50; ++cI) m = fmaxf(m, lg[cI]);
    float sum = 0.0f;
#pragma unroll
    for (int cI = 0; cI < 50; ++cI) sum += __expf(lg[cI] - m);
    float lse = m + __logf(sum);
#pragma unroll
    for (int i = 0; i < 25; ++i) {
        float2 v = {lg[2 * i] - lse, lg[2 * i + 1] - lse};
        *(float2*)&out[row * 50 + 2 * i] = v;
    }
}

extern "C" void kernel_launch(void* const* d_in, const int* in_sizes, int n_in,
                              void* d_out, int out_size, void* d_ws, size_t ws_size,
                              hipStream_t stream) {
    const int*   sentence = (const int*)d_in[0];     // (256,256)
    const float* emb      = (const float*)d_in[1];   // (50257,1024)
    const float* Wg       = (const float*)d_in[2];   // (4,1034,10)
    const float* bg       = (const float*)d_in[3];   // (4,10)
    const float* theta    = (const float*)d_in[4];   // (4,10)
    const float* Wo       = (const float*)d_in[5];   // (10,50)
    const float* bo       = (const float*)d_in[6];   // (50,)
    float* out = (float*)d_out;

    float* ws   = (float*)d_ws;
    float* Wt   = ws;                                  // 40960
    float* zs   = ws + 40960;                          // 4*65536*40
    float* outs = zs + (size_t)4 * 65536 * NC;         // 65536*10

    k_wt<<<160, 256, 0, stream>>>(Wg, Wt);
    k_gemm<<<1024, 256, 0, stream>>>(sentence, emb, Wt, zs);
    k_rnn<<<256, 64, 0, stream>>>(zs, Wg, bg, theta, outs);
    k_head<<<256, 256, 0, stream>>>(outs, Wo, bo, out);
}

// Round 3
// 382.591 us; speedup vs baseline: 1.1811x; 1.0584x over previous
//
#include <hip/hip_runtime.h>
#include <hip/hip_bf16.h>

// QLSTMClassifier: Embedding -> QLSTM (closed-form quantum layer) -> Linear -> log_softmax
// S=256 (batch==seq), E=1024, H=10, V=50257, T=50.
//
//  k_wt   : Wg x-part -> Bfg: bf16 B-fragments in MFMA B-operand layout,
//           N padded 40->48 (3 n-tiles of 16), K=1024 in 32 chunks of 32.
//  k_gemm : zs[b][t][40] = emb[idx[t*256+b]] @ W  via mfma_f32_16x16x32_bf16.
//           One wave = 16 rows; A loaded global->reg (fp32->bf16 RNE), no LDS.
//  k_rnn  : per-b recurrence. 2 waves/block: producer streams z into LDS ring
//           (16 steps/buffer, double-buffered); consumer runs the serial chain.
//  k_head : logits = hx @ W_out + b_out; log_softmax. Thread per row.
//
// ws (floats): Bfg[24576 eq] | zs[256*256*40] | outs[65536*10]  (~13.3 MB)

#define E_DIM 1024
#define H_DIM 10
#define NC 40
#define EHS 10340      // (E+H)*H per-gate Wg stride

typedef __attribute__((ext_vector_type(8))) short bf16x8;
typedef __attribute__((ext_vector_type(4))) float f32x4;

__device__ __forceinline__ unsigned short f2bf(float f) {
    unsigned u = __float_as_uint(f);
    unsigned r = u + 0x7FFFu + ((u >> 16) & 1u);   // RNE
    return (unsigned short)(r >> 16);
}

// ---------------- kernel 0: Wg -> bf16 B-fragments ----------------
// Bfg[((c*3+nt)*64+lane)*8 + j] = bf16(W[k][nc]), k=c*32+(lane>>4)*8+j, nc=nt*16+(lane&15)
__global__ __launch_bounds__(256) void k_wt(const float* __restrict__ Wg,
                                            unsigned short* __restrict__ Bfg) {
    int i = blockIdx.x * 256 + threadIdx.x;     // < 32*3*64 = 6144
    if (i >= 6144) return;
    int lane = i & 63, nt = (i >> 6) % 3, c = i / 192;
    int kg = lane >> 4, n = lane & 15;
    int nc = nt * 16 + n;
    unsigned short v[8];
#pragma unroll
    for (int j = 0; j < 8; ++j) {
        int k = c * 32 + kg * 8 + j;
        float w = 0.0f;
        if (nc < NC) {
            int g = nc / H_DIM, h = nc % H_DIM;
            w = Wg[g * EHS + k * H_DIM + h];
        }
        v[j] = f2bf(w);
    }
    bf16x8* dst = (bf16x8*)(Bfg + (size_t)i * 8);
    bf16x8 pk;
#pragma unroll
    for (int j = 0; j < 8; ++j) pk[j] = (short)v[j];
    *dst = pk;
}

// ---------------- kernel 1: gathered GEMM via MFMA, no LDS ----------------
// grid 1024 x block 256 (4 waves). Wave handles rows R0..R0+15 (same t).
__global__ __launch_bounds__(256, 4) void k_gemm(const int* __restrict__ idx,
                                                 const float* __restrict__ emb,
                                                 const unsigned short* __restrict__ Bfg,
                                                 float* __restrict__ zs) {
    const int tid = threadIdx.x;
    const int wave = tid >> 6, lane = tid & 63;
    const int R0 = (blockIdx.x * 4 + wave) * 16;
    const int m = lane & 15, q = lane >> 4;

    const int token = idx[R0 + m];
    const float* arow = emb + (size_t)token * E_DIM + q * 8;

    f32x4 acc0 = {0.f, 0.f, 0.f, 0.f}, acc1 = acc0, acc2 = acc0;

#pragma unroll 2
    for (int c = 0; c < 32; ++c) {
        float4 a0 = *(const float4*)(arow + c * 32);
        float4 a1 = *(const float4*)(arow + c * 32 + 4);
        bf16x8 b0 = *(const bf16x8*)(Bfg + ((size_t)(c * 3 + 0) * 64 + lane) * 8);
        bf16x8 b1 = *(const bf16x8*)(Bfg + ((size_t)(c * 3 + 1) * 64 + lane) * 8);
        bf16x8 b2 = *(const bf16x8*)(Bfg + ((size_t)(c * 3 + 2) * 64 + lane) * 8);
        bf16x8 af;
        af[0] = (short)f2bf(a0.x); af[1] = (short)f2bf(a0.y);
        af[2] = (short)f2bf(a0.z); af[3] = (short)f2bf(a0.w);
        af[4] = (short)f2bf(a1.x); af[5] = (short)f2bf(a1.y);
        af[6] = (short)f2bf(a1.z); af[7] = (short)f2bf(a1.w);
        acc0 = __builtin_amdgcn_mfma_f32_16x16x32_bf16(af, b0, acc0, 0, 0, 0);
        acc1 = __builtin_amdgcn_mfma_f32_16x16x32_bf16(af, b1, acc1, 0, 0, 0);
        acc2 = __builtin_amdgcn_mfma_f32_16x16x32_bf16(af, b2, acc2, 0, 0, 0);
    }

    // C/D layout: col = lane&15, row = (lane>>4)*4 + reg
    const int t = R0 >> 8;
    const int bbase = (R0 & 255) + q * 4;
#pragma unroll
    for (int i = 0; i < 4; ++i) {
        int b = bbase + i;
        size_t o = ((size_t)b * 256 + t) * NC;
        zs[o + m] = acc0[i];
        zs[o + 16 + m] = acc1[i];
        if (m < 8) zs[o + 32 + m] = acc2[i];
    }
}

// ---------------- kernel 2: QLSTM recurrence, producer/consumer ----------------
template <int CTRL>
__device__ __forceinline__ float dpp1(float x) {
    // shifted value; out-of-range lanes keep identity 1.0 (old value, bound_ctrl=false)
    return __int_as_float(__builtin_amdgcn_update_dpp(
        __float_as_int(1.0f), __float_as_int(x), CTRL, 0xF, 0xF, false));
}
#define ROW_SHR(n) (0x110 + (n))
#define ROW_SHL(n) (0x100 + (n))

__device__ __forceinline__ float rdlane(float v, int l) {
    return __int_as_float(__builtin_amdgcn_readlane(__float_as_int(v), l));
}

__global__ __launch_bounds__(128) void k_rnn(const float* __restrict__ zs,
                                             const float* __restrict__ Wg,
                                             const float* __restrict__ bg,
                                             const float* __restrict__ theta,
                                             float* __restrict__ outs) {
    __shared__ float zbuf[2][640];   // 16 steps x 40 per buffer
    const int tid = threadIdx.x;
    const int b = blockIdx.x;

    if (tid >= 64) {
        // ---- producer wave: stream zs[b] 16 steps at a time ----
        const int p = tid - 64;
        const float* src = zs + (size_t)b * 256 * NC;
#pragma unroll
        for (int k = 0; k < 10; ++k) zbuf[0][p + k * 64] = src[p + k * 64];
        __syncthreads();
        for (int blk = 0; blk < 16; ++blk) {
            if (blk + 1 < 16) {
                const float* s2 = src + (blk + 1) * 640;
                float v[10];
#pragma unroll
                for (int k = 0; k < 10; ++k) v[k] = s2[p + k * 64];
#pragma unroll
                for (int k = 0; k < 10; ++k) zbuf[(blk + 1) & 1][p + k * 64] = v[k];
            }
            __syncthreads();
        }
    } else {
        // ---- consumer wave: the serial chain ----
        const int lane = tid;
        const int r = lane >> 4;            // gate 0..3 (f,i,g,o)
        const int h = lane & 15;            // wire; valid < 10
        const int hc = (h < 10) ? h : 9;
        const int cidx = r * 10 + hc;

        float Wh[10];
#pragma unroll
        for (int j = 0; j < 10; ++j) Wh[j] = Wg[r * EHS + (E_DIM + j) * H_DIM + hc];
        const float bias = bg[cidx] + theta[cidx];

        const float kk = (r == 2) ? 2.0f : -1.0f;   // tanh : sigmoid
        const float aa = (r == 2) ? 1.0f : 0.0f;
        const float bb = (r == 2) ? -2.0f : 1.0f;

        float cx = 0.0f, hx = 0.0f;
        __syncthreads();

        for (int blk = 0; blk < 16; ++blk) {
            const float* zb = zbuf[blk & 1];
            float zv = zb[cidx];
#pragma unroll 4
            for (int s = 0; s < 16; ++s) {
                float znext = zb[((s < 15) ? (s + 1) * 40 : s * 40) + cidx];

                // hx[0..9] live on lanes 0..9 -> SGPR broadcasts
                float hv0 = rdlane(hx, 0), hv1 = rdlane(hx, 1), hv2 = rdlane(hx, 2),
                      hv3 = rdlane(hx, 3), hv4 = rdlane(hx, 4), hv5 = rdlane(hx, 5),
                      hv6 = rdlane(hx, 6), hv7 = rdlane(hx, 7), hv8 = rdlane(hx, 8),
                      hv9 = rdlane(hx, 9);
                float d0 = fmaf(hv0, Wh[0], fmaf(hv2, Wh[2],
                           fmaf(hv4, Wh[4], fmaf(hv6, Wh[6], hv8 * Wh[8]))));
                float d1 = fmaf(hv1, Wh[1], fmaf(hv3, Wh[3],
                           fmaf(hv5, Wh[5], fmaf(hv7, Wh[7], hv9 * Wh[9]))));
                float z = (zv + bias) + (d0 + d1);

                float cc = __builtin_amdgcn_cosf(z * 0.15915494309189535f);

                // inclusive prefix product P[h] = prod_{j<=h} c_j
                float pp = cc;
                pp *= dpp1<ROW_SHR(1)>(pp);
                pp *= dpp1<ROW_SHR(2)>(pp);
                pp *= dpp1<ROW_SHR(4)>(pp);
                pp *= dpp1<ROW_SHR(8)>(pp);
                // suffix product (pad lanes h>=10 with identity)
                float ss = (h < 10) ? cc : 1.0f;
                ss *= dpp1<ROW_SHL(1)>(ss);
                ss *= dpp1<ROW_SHL(2)>(ss);
                ss *= dpp1<ROW_SHL(4)>(ss);
                ss *= dpp1<ROW_SHL(8)>(ss);
                float tl = dpp1<ROW_SHL(1)>(ss);     // lane 0 -> prod_{j>=1}
                float qv = (h == 0) ? tl : pp;

                float e = __expf(kk * qv);
                float act = fmaf(bb, __builtin_amdgcn_rcpf(1.0f + e), aa);

                // gather f,i,g,o for wire h (lanes h, 16+h, 32+h, 48+h)
                float fv = __shfl(act, h);
                float iv = __shfl(act, 16 + h);
                float gv = __shfl(act, 32 + h);
                float ov = __shfl(act, 48 + h);

                cx = fmaf(fv, cx, iv * gv);
                float e2 = __expf(2.0f * cx);
                float th = fmaf(-2.0f, __builtin_amdgcn_rcpf(1.0f + e2), 1.0f);
                hx = ov * th;

                int t = blk * 16 + s;
                if (lane < 10) outs[((size_t)t * 256 + b) * H_DIM + lane] = hx;
                zv = znext;
            }
            __syncthreads();
        }
    }
}

// ---------------- kernel 3: hidden2tag + log_softmax, thread per row ----------------
__global__ __launch_bounds__(256) void k_head(const float* __restrict__ outs,
                                              const float* __restrict__ Wo,
                                              const float* __restrict__ bo,
                                              float* __restrict__ out) {
    const size_t row = blockIdx.x * 256 + threadIdx.x;   // < 65536
    float hx[10];
#pragma unroll
    for (int i = 0; i < 5; ++i) {
        float2 v = *(const float2*)&outs[row * H_DIM + 2 * i];
        hx[2 * i] = v.x; hx[2 * i + 1] = v.y;
    }
    float lg[50];
#pragma unroll
    for (int cI = 0; cI < 50; ++cI) {
        float l = bo[cI];
#pragma unroll
        for (int j = 0; j < 10; ++j) l = fmaf(hx[j], Wo[j * 50 + cI], l);
        lg[cI] = l;
    }
    float m = lg[0];
#pragma unroll
    for (int cI = 1; cI < 50; ++cI) m = fmaxf(m, lg[cI]);
    float sum = 0.0f;
#pragma unroll
    for (int cI = 0; cI < 50; ++cI) sum += __expf(lg[cI] - m);
    float lse = m + __logf(sum);
#pragma unroll
    for (int i = 0; i < 25; ++i) {
        float2 v = {lg[2 * i] - lse, lg[2 * i + 1] - lse};
        *(float2*)&out[row * 50 + 2 * i] = v;
    }
}

extern "C" void kernel_launch(void* const* d_in, const int* in_sizes, int n_in,
                              void* d_out, int out_size, void* d_ws, size_t ws_size,
                              hipStream_t stream) {
    const int*   sentence = (const int*)d_in[0];     // (256,256)
    const float* emb      = (const float*)d_in[1];   // (50257,1024)
    const float* Wg       = (const float*)d_in[2];   // (4,1034,10)
    const float* bg       = (const float*)d_in[3];   // (4,10)
    const float* theta    = (const float*)d_in[4];   // (4,10)
    const float* Wo       = (const float*)d_in[5];   // (10,50)
    const float* bo       = (const float*)d_in[6];   // (50,)
    float* out = (float*)d_out;

    float* ws = (float*)d_ws;
    unsigned short* Bfg = (unsigned short*)ws;            // 49152 shorts = 24576 floats
    float* zs   = ws + 24576;                             // 256*256*40
    float* outs = zs + (size_t)256 * 256 * NC;            // 65536*10

    k_wt<<<24, 256, 0, stream>>>(Wg, Bfg);
    k_gemm<<<1024, 256, 0, stream>>>(sentence, emb, Bfg, zs);
    k_rnn<<<256, 128, 0, stream>>>(zs, Wg, bg, theta, outs);
    k_head<<<256, 256, 0, stream>>>(outs, Wo, bo, out);
}